// Round 18
// baseline (672.941 us; speedup 1.0000x reference)
//
#include <hip/hip_runtime.h>

typedef unsigned short u16;
typedef unsigned int u32;
typedef __attribute__((ext_vector_type(8))) short sv8;   // 8 bf16
typedef __attribute__((ext_vector_type(4))) float fv4;   // MFMA acc
typedef __attribute__((ext_vector_type(4))) unsigned short us4;
typedef __attribute__((ext_vector_type(2))) unsigned short us2;

__device__ __forceinline__ u16 f2b(float x) {
    union { float f; u32 u; } a; a.f = x;
    u32 r = a.u + 0x7FFFu + ((a.u >> 16) & 1u);
    return (u16)(r >> 16);
}
__device__ __forceinline__ float b2f(u16 h) {
    union { u32 u; float f; } a; a.u = ((u32)h) << 16;
    return a.f;
}

// async global->LDS, 16B per lane
__device__ __forceinline__ void gll16(const void* g, void* l) {
    __builtin_amdgcn_global_load_lds((__attribute__((address_space(1))) void*)g,
                                     (__attribute__((address_space(3))) void*)l,
                                     16, 0, 0);
}

// ---------------------------------------------------------------------------
// Node GEMM (R16 champion): tile 128x64, BK=64, XOR-granule-swizzled LDS,
// gll16 staging (bf16 A) / reg-staged transform (AF32 / AAFF BN-fold);
// Cs aliases As/Bs after K-loop; T1 XCD swizzle; EPI 0/1/3; STATS col sums.
// ---------------------------------------------------------------------------
template<bool AF32, bool AAFF, int EPI, bool STATS>
__global__ __launch_bounds__(256) void k_gemm(
    const void* __restrict__ Aptr, const u16* __restrict__ Wt,
    const float* __restrict__ bias, void* __restrict__ Cptr,
    int M, int K, int F,
    const float* __restrict__ sc, const float* __restrict__ sh,
    float* __restrict__ sums, float* __restrict__ sumsq)
{
    __shared__ u16 smem[12288];           // As 8192 | Bs 4096 (u16 units)
    u16* As = smem;
    u16* Bs = smem + 8192;
    u16* Cs = smem;                       // [128][68] aliased
    const int t = threadIdx.x, w = t >> 6, l = t & 63;

    const int gx = gridDim.x;
    const int nwg = gx * gridDim.y;
    const int bid = blockIdx.y * gx + blockIdx.x;
    const int qq = nwg >> 3, rr = nwg & 7;
    const int xcd = bid & 7, jj = bid >> 3;
    const int swz = (xcd < rr ? xcd * (qq + 1) : rr * (qq + 1) + (xcd - rr) * qq) + jj;
    const int n0 = (swz % gx) * 64;
    const int m0 = (swz / gx) * 128;

    fv4 acc0[4] = {}, acc1[4] = {};

    for (int k0 = 0; k0 < K; k0 += 64) {
        #pragma unroll
        for (int i = 0; i < 2; ++i) {
            const int sb = (w * 2 + i) << 6;
            const int slot = sb + l;
            const int row = slot >> 3;
            const int gs = (slot & 7) ^ (row & 7);
            gll16(Wt + (size_t)(n0 + row) * K + k0 + gs * 8, Bs + sb * 8);
        }
        if constexpr (!AF32 && !AAFF) {
            const u16* Ab = (const u16*)Aptr;
            #pragma unroll
            for (int i = 0; i < 4; ++i) {
                const int sb = (w * 4 + i) << 6;
                const int slot = sb + l;
                const int row = slot >> 3;
                const int gs = (slot & 7) ^ (row & 7);
                int rg = m0 + row; if (rg > M - 1) rg = M - 1;
                gll16(Ab + (size_t)rg * K + k0 + gs * 8, As + sb * 8);
            }
        } else {
            const int row = t >> 1;
            int rg = m0 + row; if (rg > M - 1) rg = M - 1;
            const size_t gr = (size_t)rg;
            #pragma unroll
            for (int i = 0; i < 4; ++i) {
                const int g = ((t & 1) << 2) + i;
                const int kb = k0 + (g << 3);
                sv8 av;
                if constexpr (AF32) {
                    const float* Af = (const float*)Aptr;
                    fv4 u0 = *(const fv4*)(Af + gr * K + kb);
                    fv4 u1 = *(const fv4*)(Af + gr * K + kb + 4);
                    #pragma unroll
                    for (int j = 0; j < 4; ++j) { av[j] = (short)f2b(u0[j]); av[j + 4] = (short)f2b(u1[j]); }
                } else {
                    sv8 v = *(const sv8*)((const u16*)Aptr + gr * K + kb);
                    fv4 c0 = *(const fv4*)(sc + kb), c1 = *(const fv4*)(sc + kb + 4);
                    fv4 d0 = *(const fv4*)(sh + kb), d1 = *(const fv4*)(sh + kb + 4);
                    #pragma unroll
                    for (int j = 0; j < 4; ++j) {
                        av[j]     = (short)f2b(fmaxf(b2f((u16)v[j])     * c0[j] + d0[j], 0.f));
                        av[j + 4] = (short)f2b(fmaxf(b2f((u16)v[j + 4]) * c1[j] + d1[j], 0.f));
                    }
                }
                const int gs = g ^ (row & 7);
                *(sv8*)&As[(row * 8 + gs) * 8] = av;
            }
        }
        __syncthreads();

        #pragma unroll
        for (int kk = 0; kk < 2; ++kk) {
            const int ga = (kk << 2) + (l >> 4);
            const int Ar0 = (w << 4) + (l & 15);
            const int Ar1 = 64 + Ar0;
            sv8 a0 = *(const sv8*)&As[(Ar0 * 8 + (ga ^ (Ar0 & 7))) * 8];
            sv8 a1 = *(const sv8*)&As[(Ar1 * 8 + (ga ^ (Ar1 & 7))) * 8];
            #pragma unroll
            for (int ct = 0; ct < 4; ++ct) {
                const int Brow = (ct << 4) + (l & 15);
                sv8 b = *(const sv8*)&Bs[(Brow * 8 + (ga ^ (Brow & 7))) * 8];
                acc0[ct] = __builtin_amdgcn_mfma_f32_16x16x32_bf16(a0, b, acc0[ct], 0, 0, 0);
                acc1[ct] = __builtin_amdgcn_mfma_f32_16x16x32_bf16(a1, b, acc1[ct], 0, 0, 0);
            }
        }
        __syncthreads();
    }

    const int lr0 = (w << 4) + ((l >> 4) << 2);
    #pragma unroll
    for (int ct = 0; ct < 4; ++ct) {
        const int col = (ct << 4) + (l & 15);
        const float bv = bias[n0 + col];
        float s = 0.f, s2 = 0.f;
        #pragma unroll
        for (int h = 0; h < 2; ++h) {
            #pragma unroll
            for (int r = 0; r < 4; ++r) {
                const int lrow = (h << 6) + lr0 + r;
                const bool valid = (m0 + lrow) < M;
                float v = (h ? acc1[ct][r] : acc0[ct][r]) + bv;
                if constexpr (STATS) { if (valid) { s += v; s2 += v * v; } }
                if constexpr (EPI == 1) v = fmaxf(v, 0.f);
                if constexpr (EPI == 3) {
                    if (valid) ((float*)Cptr)[(size_t)(m0 + lrow) * F + n0 + col] = v;
                } else {
                    Cs[lrow * 68 + col] = f2b(v);
                }
            }
        }
        if constexpr (STATS) {
            s  += __shfl_xor(s, 16);  s  += __shfl_xor(s, 32);
            s2 += __shfl_xor(s2, 16); s2 += __shfl_xor(s2, 32);
            if (l < 16) { unsafeAtomicAdd(&sums[n0 + col], s); unsafeAtomicAdd(&sumsq[n0 + col], s2); }
        }
    }
    if constexpr (EPI != 3) {
        __syncthreads();
        const int row = t >> 1, c0 = (t & 1) << 5;
        if (m0 + row < M) {
            u16* Cb = (u16*)Cptr + (size_t)(m0 + row) * F + n0 + c0;
            #pragma unroll
            for (int j = 0; j < 4; ++j)
                *(sv8*)(Cb + j * 8) = *(const sv8*)&Cs[row * 68 + c0 + j * 8];
        }
    }
}

// ---------------------------------------------------------------------------
// Edge GEMM (R13/R16-proven): e[p][.] = bf16(ea[perm[p]]) @ Wt^T + bias.
// Bs-only LDS; A direct to registers; shfl-pack u32 stores.
// ---------------------------------------------------------------------------
template<int FN>
__global__ __launch_bounds__(256) void k_egemm3(
    const float* __restrict__ ea, const int* __restrict__ perm,
    const u16* __restrict__ Wt, const float* __restrict__ bias,
    u16* __restrict__ Cbuf)
{
    __shared__ u16 Bs[FN * 64];
    const int t = threadIdx.x, w = t >> 6, l = t & 63;
    const int m0 = blockIdx.x * 64;

    constexpr int BISS = FN / 32;        // B: FN rows x 8 granules of 16B
    #pragma unroll
    for (int i = 0; i < BISS; ++i) {
        int slot = ((w * BISS + i) << 6) + l;
        int row = slot >> 3, g = (slot & 7) ^ (row & 7);
        gll16(Wt + (size_t)row * 64 + g * 8, Bs + ((w * BISS + i) << 6) * 8);
    }

    const int g0 = l >> 4;
    const int gr = m0 + (w << 4) + (l & 15);
    const int prow = perm[gr];
    const float* ar = ea + (size_t)prow * 64 + (g0 << 3);
    fv4 u0 = *(const fv4*)ar;
    fv4 u1 = *(const fv4*)(ar + 4);
    fv4 u2 = *(const fv4*)(ar + 32);
    fv4 u3 = *(const fv4*)(ar + 36);
    sv8 a0, a1;
    #pragma unroll
    for (int j = 0; j < 4; ++j) {
        a0[j] = (short)f2b(u0[j]); a0[j + 4] = (short)f2b(u1[j]);
        a1[j] = (short)f2b(u2[j]); a1[j + 4] = (short)f2b(u3[j]);
    }
    __syncthreads();                     // Bs resident (vmcnt drained)

    fv4 acc[FN / 16];
    #pragma unroll
    for (int ct = 0; ct < FN / 16; ++ct) {
        int Brow = (ct << 4) + (l & 15);
        sv8 b0 = *(const sv8*)&Bs[(Brow * 8 + ((g0)     ^ (Brow & 7))) * 8];
        sv8 b1 = *(const sv8*)&Bs[(Brow * 8 + ((g0 + 4) ^ (Brow & 7))) * 8];
        fv4 z = {};
        z = __builtin_amdgcn_mfma_f32_16x16x32_bf16(a0, b0, z, 0, 0, 0);
        acc[ct] = __builtin_amdgcn_mfma_f32_16x16x32_bf16(a1, b1, z, 0, 0, 0);
    }

    const int r0 = (w << 4) + ((l >> 4) << 2);
    #pragma unroll
    for (int ct = 0; ct < FN / 16; ++ct) {
        const int col = (ct << 4) + (l & 15);
        const float bv = bias[col];
        #pragma unroll
        for (int r = 0; r < 4; ++r) {
            const int row = m0 + r0 + r;
            u32 my = (u32)f2b(acc[ct][r] + bv);
            u32 ot = (u32)__shfl_xor((int)my, 1);
            if (!(l & 1))
                *(u32*)(Cbuf + (size_t)row * FN + col) = (my & 0xFFFFu) | (ot << 16);
        }
    }
}

// --------------------------- CSR build (by dst) ----------------------------
__global__ void k_hist(const int* __restrict__ dst, int* __restrict__ counts, int E) {
    int i = blockIdx.x * 256 + threadIdx.x;
    if (i < E) atomicAdd(&counts[dst[i]], 1);
}

__global__ __launch_bounds__(256) void k_psum(const int* __restrict__ counts,
                                              int* __restrict__ bsum, int n) {
    int i = blockIdx.x * 256 + threadIdx.x;
    int v = (i < n) ? counts[i] : 0;
    #pragma unroll
    for (int o = 1; o < 64; o <<= 1) v += __shfl_xor(v, o);
    __shared__ int ws[4];
    if ((threadIdx.x & 63) == 0) ws[threadIdx.x >> 6] = v;
    __syncthreads();
    if (threadIdx.x == 0) bsum[blockIdx.x] = ws[0] + ws[1] + ws[2] + ws[3];
}

__global__ __launch_bounds__(256) void k_bscan(const int* __restrict__ bsum,
                                               int* __restrict__ boff, int nb) {
    __shared__ int sm[256];
    int t = threadIdx.x;
    int v = (t < nb) ? bsum[t] : 0;
    sm[t] = v; __syncthreads();
    #pragma unroll
    for (int o = 1; o < 256; o <<= 1) {
        int u = (t >= o) ? sm[t - o] : 0;
        __syncthreads();
        sm[t] += u;
        __syncthreads();
    }
    if (t < nb) boff[t] = sm[t] - v;
}

__global__ __launch_bounds__(256) void k_windp(const int* __restrict__ counts,
                                               const int* __restrict__ boff,
                                               int* __restrict__ indptr,
                                               int* __restrict__ cursors, int n) {
    __shared__ int sm[256];
    const int t = threadIdx.x, i = blockIdx.x * 256 + t;
    int v = (i < n) ? counts[i] : 0;
    sm[t] = v; __syncthreads();
    #pragma unroll
    for (int o = 1; o < 256; o <<= 1) {
        int u = (t >= o) ? sm[t - o] : 0;
        __syncthreads();
        sm[t] += u;
        __syncthreads();
    }
    int excl = sm[t] - v + boff[blockIdx.x];
    if (i < n) { indptr[i] = excl; cursors[i] = excl; }
    if (i == n - 1) indptr[n] = excl + v;
}

__global__ void k_scatter(const int* __restrict__ dst, const int* __restrict__ src,
                          int* __restrict__ cursors, int* __restrict__ perm,
                          int* __restrict__ srcp, int E) {
    int i = blockIdx.x * 256 + threadIdx.x;
    if (i < E) {
        int p = atomicAdd(&cursors[dst[i]], 1);
        perm[p] = i;
        srcp[p] = src[i];
    }
}

// ------------- softmax aggregation: msg = relu(e[p] + h[src[p]]) + eps -----
// Batched 4-edge pipeline: issue all 4 srcp + 8 vector loads (8 outstanding
// VMEM ops), then accumulate. Static register indices (unrolled). Same
// accumulation order as before -> bit-identical results.
template<int F, int VPT>
__global__ __launch_bounds__(256) void k_agg(
    const u16* __restrict__ e, const u16* __restrict__ hhd,
    const int* __restrict__ srcp, const int* __restrict__ indptr,
    u16* __restrict__ out, int N)
{
    const int nid = blockIdx.x * 4 + (threadIdx.x >> 6);
    if (nid >= N) return;
    const int c0 = (threadIdx.x & 63) * VPT;
    const int S = 2 * F;
    const int p0 = indptr[nid], p1 = indptr[nid + 1];
    float den[VPT] = {}, num[VPT] = {};

    for (int p = p0; p < p1; p += 4) {
        const int cnt = p1 - p;           // >=1
        int ss[4];
        #pragma unroll
        for (int j = 0; j < 4; ++j)
            ss[j] = (j < cnt) ? srcp[p + j] : 0;

        u16 ev[4][VPT], hv[4][VPT];
        #pragma unroll
        for (int j = 0; j < 4; ++j) {
            if (j < cnt) {
                if constexpr (VPT == 4) {
                    *(us4*)ev[j] = *(const us4*)&e[(size_t)(p + j) * F + c0];
                    *(us4*)hv[j] = *(const us4*)&hhd[(size_t)ss[j] * S + c0];
                } else {
                    *(us2*)ev[j] = *(const us2*)&e[(size_t)(p + j) * F + c0];
                    *(us2*)hv[j] = *(const us2*)&hhd[(size_t)ss[j] * S + c0];
                }
            }
        }
        #pragma unroll
        for (int j = 0; j < 4; ++j) {
            if (j < cnt) {
                #pragma unroll
                for (int k = 0; k < VPT; ++k) {
                    float x = fmaxf(b2f(ev[j][k]) + b2f(hv[j][k]), 0.f) + 1e-7f;
                    float ex = __expf(x);
                    den[k] += ex;
                    num[k] += ex * x;
                }
            }
        }
    }

    #pragma unroll
    for (int j = 0; j < VPT; ++j) {
        float o = num[j] / (den[j] + 1e-16f) + b2f(hhd[(size_t)nid * S + F + c0 + j]);
        out[(size_t)nid * F + c0 + j] = f2b(o);
    }
}

// ------------------- all weight converts in one kernel ---------------------
struct WtDesc { const float* W; u16* D; int K; int F; int end; };
struct WtPack { WtDesc d[10]; };

__global__ void k_wtall(WtPack p, int total) {
    int i = blockIdx.x * 256 + threadIdx.x;
    if (i >= total) return;
    int s = 0, base = 0;
    while (i >= p.d[s].end) { base = p.d[s].end; ++s; }
    int loc = i - base;
    int K = p.d[s].K, F = p.d[s].F;
    int f = loc / K, k = loc - f * K;
    p.d[s].D[loc] = f2b(p.d[s].W[(size_t)k * F + f]);
}

// ---- bias concats ---------------------------------------------------------
__global__ void k_bcat(const float* __restrict__ bsrc1, const float* __restrict__ bdst1,
                       const float* __restrict__ bsrc2, const float* __restrict__ bdst2,
                       float* __restrict__ bcat1, float* __restrict__ bcat2) {
    int t = threadIdx.x;
    bcat1[t] = bsrc1[t];
    bcat1[256 + t] = bdst1[t];
    if (t < 128) {
        bcat2[t] = bsrc2[t];
        bcat2[128 + t] = bdst2[t];
    }
}

// ----------------------------- BN finalize ---------------------------------
__global__ void k_bnfinal(const float* __restrict__ sums, const float* __restrict__ sumsq,
                          const float* __restrict__ g, const float* __restrict__ bt,
                          float* __restrict__ scale, float* __restrict__ shift,
                          int C, float invN)
{
    int c = blockIdx.x * 256 + threadIdx.x;
    if (c < C) {
        float mu  = sums[c] * invN;
        float var = sumsq[c] * invN - mu * mu;
        float s   = g[c] * rsqrtf(var + 1e-5f);
        scale[c] = s;
        shift[c] = bt[c] - mu * s;
    }
}

// ---------------------------------------------------------------------------
extern "C" void kernel_launch(void* const* d_in, const int* in_sizes, int n_in,
                              void* d_out, int out_size, void* d_ws, size_t ws_size,
                              hipStream_t stream)
{
    const int IN = 128, HID = 256, OUT = 128, ED = 64;
    const int N = in_sizes[0] / IN;
    const int E = in_sizes[1] / 2;

    const float* x   = (const float*)d_in[0];
    const int*   src = (const int*)d_in[1];
    const int*   dst = src + E;
    const float* ea  = (const float*)d_in[2];
    auto F32 = [&](int i) { return (const float*)d_in[i]; };
    const float *Wsrc1 = F32(3),  *bsrc1 = F32(4),  *Wdst1 = F32(5),  *bdst1 = F32(6),
                *We1   = F32(7),  *be1   = F32(8),  *W11   = F32(9),  *b11   = F32(10),
                *g1    = F32(11), *bt1   = F32(12), *W21   = F32(13), *b21   = F32(14);
    const float *Wsrc2 = F32(15), *bsrc2 = F32(16), *Wdst2 = F32(17), *bdst2 = F32(18),
                *We2   = F32(19), *be2   = F32(20), *W12   = F32(21), *b12   = F32(22),
                *g2    = F32(23), *bt2   = F32(24), *W22   = F32(25), *b22   = F32(26);

    char* wp = (char*)d_ws;
    auto carve = [&](size_t bytes) -> void* {
        void* r = (void*)wp; wp += (bytes + 255) & ~(size_t)255; return r;
    };
    u16* wcat1  = (u16*)carve((size_t)HID * IN * 2);
    u16* wdst1t = (u16*)carve((size_t)HID * IN * 2);
    u16* we1t   = (u16*)carve((size_t)HID * ED * 2);
    u16* w11t   = (u16*)carve((size_t)(2 * HID) * HID * 2);
    u16* w21t   = (u16*)carve((size_t)HID * (2 * HID) * 2);
    u16* wcat2  = (u16*)carve((size_t)OUT * HID * 2);
    u16* wdst2t = (u16*)carve((size_t)OUT * HID * 2);
    u16* we2t   = (u16*)carve((size_t)OUT * ED * 2);
    u16* w12t   = (u16*)carve((size_t)(2 * OUT) * OUT * 2);
    u16* w22t   = (u16*)carve((size_t)OUT * (2 * OUT) * 2);
    int* counts  = (int*)carve((size_t)N * 4);
    int* indptr  = (int*)carve((size_t)(N + 1) * 4);
    int* cursors = (int*)carve((size_t)N * 4);
    int* perm    = (int*)carve((size_t)E * 4);
    int* srcp    = (int*)carve((size_t)E * 4);
    int* bsum    = (int*)carve((size_t)256 * 4);
    int* boff    = (int*)carve((size_t)256 * 4);
    u16* hhd  = (u16*)carve((size_t)N * 512 * 2);
    u16* x2   = (u16*)carve((size_t)N * HID * 2);
    u16* ebuf = (u16*)carve((size_t)E * HID * 2);   // e rows; h1 aliases this
    float* stats1 = (float*)carve((size_t)1024 * 4);
    float* stats2 = (float*)carve((size_t)512 * 4);
    float* ss1    = (float*)carve((size_t)1024 * 4);
    float* ss2    = (float*)carve((size_t)512 * 4);
    float* bcat1  = (float*)carve((size_t)512 * 4);
    float* bcat2  = (float*)carve((size_t)256 * 4);
    u16* h1 = ebuf;   // lifetimes strictly interleave: e-L1, h1-L1, e-L2, h1-L2

    hipMemsetAsync(counts, 0, (size_t)N * 4, stream);
    hipMemsetAsync(stats1, 0, (size_t)(1024 + 512) * 4, stream);
    k_hist<<<dim3((E + 255) / 256), dim3(256), 0, stream>>>(dst, counts, E);
    const int nb = (N + 255) / 256;
    k_psum<<<dim3(nb), dim3(256), 0, stream>>>(counts, bsum, N);
    k_bscan<<<dim3(1), dim3(256), 0, stream>>>(bsum, boff, nb);
    k_windp<<<dim3(nb), dim3(256), 0, stream>>>(counts, boff, indptr, cursors, N);
    k_scatter<<<dim3((E + 255) / 256), dim3(256), 0, stream>>>(dst, src, cursors, perm, srcp, E);

    WtPack wpk; int acc_end = 0;
    auto addw = [&](int idx, const float* W, u16* D, int K, int F) {
        acc_end += K * F;
        wpk.d[idx] = WtDesc{W, D, K, F, acc_end};
    };
    addw(0, Wsrc1, wcat1,  IN, HID);   addw(1, Wdst1, wdst1t, IN, HID);
    addw(2, We1,   we1t,   ED, HID);   addw(3, W11,   w11t,   HID, 2 * HID);
    addw(4, W21,   w21t,   2 * HID, HID);
    addw(5, Wsrc2, wcat2,  HID, OUT);  addw(6, Wdst2, wdst2t, HID, OUT);
    addw(7, We2,   we2t,   ED, OUT);   addw(8, W12,   w12t,   OUT, 2 * OUT);
    addw(9, W22,   w22t,   2 * OUT, OUT);
    k_wtall<<<dim3((acc_end + 255) / 256), dim3(256), 0, stream>>>(wpk, acc_end);
    k_bcat<<<dim3(1), dim3(256), 0, stream>>>(bsrc1, bdst1, bsrc2, bdst2, bcat1, bcat2);

    const int gm = (N + 127) / 128;

    // ---------------- Layer 1 ----------------
    k_gemm<true, false, 0, false><<<dim3(8, gm), dim3(256), 0, stream>>>(
        x, wcat1, bcat1, hhd, N, IN, 512, nullptr, nullptr, nullptr, nullptr);
    k_egemm3<256><<<dim3(E / 64), dim3(256), 0, stream>>>(ea, perm, we1t, be1, ebuf);
    k_agg<256, 4><<<dim3((N + 3) / 4), dim3(256), 0, stream>>>(ebuf, hhd, srcp, indptr, x2, N);
    k_gemm<false, false, 0, true><<<dim3(8, gm), dim3(256), 0, stream>>>(
        x2, w11t, b11, h1, N, HID, 512, nullptr, nullptr, stats1, stats1 + 512);
    k_bnfinal<<<dim3(2), dim3(256), 0, stream>>>(
        stats1, stats1 + 512, g1, bt1, ss1, ss1 + 512, 512, 1.f / N);
    k_gemm<false, true, 1, false><<<dim3(4, gm), dim3(256), 0, stream>>>(
        h1, w21t, b21, x2, N, 512, HID, ss1, ss1 + 512, nullptr, nullptr);

    // ---------------- Layer 2 ----------------
    k_gemm<false, false, 0, false><<<dim3(4, gm), dim3(256), 0, stream>>>(
        x2, wcat2, bcat2, hhd, N, HID, 256, nullptr, nullptr, nullptr, nullptr);
    k_egemm3<128><<<dim3(E / 64), dim3(256), 0, stream>>>(ea, perm, we2t, be2, ebuf);
    k_agg<128, 2><<<dim3((N + 3) / 4), dim3(256), 0, stream>>>(ebuf, hhd, srcp, indptr, x2, N);
    k_gemm<false, false, 0, true><<<dim3(4, gm), dim3(256), 0, stream>>>(
        x2, w12t, b12, h1, N, OUT, 256, nullptr, nullptr, stats2, stats2 + 256);
    k_bnfinal<<<dim3(1), dim3(256), 0, stream>>>(
        stats2, stats2 + 256, g2, bt2, ss2, ss2 + 256, 256, 1.f / N);
    k_gemm<false, true, 3, false><<<dim3(2, gm), dim3(256), 0, stream>>>(
        h1, w22t, b22, d_out, N, HID, OUT, ss2, ss2 + 256, nullptr, nullptr);
}

// Round 19
// 650.510 us; speedup vs baseline: 1.0345x; 1.0345x over previous
//
#include <hip/hip_runtime.h>

typedef unsigned short u16;
typedef unsigned int u32;
typedef __attribute__((ext_vector_type(8))) short sv8;   // 8 bf16
typedef __attribute__((ext_vector_type(4))) float fv4;   // MFMA acc
typedef __attribute__((ext_vector_type(4))) unsigned short us4;
typedef __attribute__((ext_vector_type(2))) unsigned short us2;

__device__ __forceinline__ u16 f2b(float x) {
    union { float f; u32 u; } a; a.f = x;
    u32 r = a.u + 0x7FFFu + ((a.u >> 16) & 1u);
    return (u16)(r >> 16);
}
__device__ __forceinline__ float b2f(u16 h) {
    union { u32 u; float f; } a; a.u = ((u32)h) << 16;
    return a.f;
}

// async global->LDS, 16B per lane
__device__ __forceinline__ void gll16(const void* g, void* l) {
    __builtin_amdgcn_global_load_lds((__attribute__((address_space(1))) void*)g,
                                     (__attribute__((address_space(3))) void*)l,
                                     16, 0, 0);
}

// ---------------------------------------------------------------------------
// Node GEMM (R16 champion): tile 128x64, BK=64, XOR-granule-swizzled LDS,
// gll16 staging (bf16 A) / reg-staged transform (AF32 / AAFF BN-fold);
// Cs aliases As/Bs after K-loop; T1 XCD swizzle; EPI 0/1/3; STATS col sums.
// ---------------------------------------------------------------------------
template<bool AF32, bool AAFF, int EPI, bool STATS>
__global__ __launch_bounds__(256) void k_gemm(
    const void* __restrict__ Aptr, const u16* __restrict__ Wt,
    const float* __restrict__ bias, void* __restrict__ Cptr,
    int M, int K, int F,
    const float* __restrict__ sc, const float* __restrict__ sh,
    float* __restrict__ sums, float* __restrict__ sumsq)
{
    __shared__ u16 smem[12288];           // As 8192 | Bs 4096 (u16 units)
    u16* As = smem;
    u16* Bs = smem + 8192;
    u16* Cs = smem;                       // [128][68] aliased
    const int t = threadIdx.x, w = t >> 6, l = t & 63;

    const int gx = gridDim.x;
    const int nwg = gx * gridDim.y;
    const int bid = blockIdx.y * gx + blockIdx.x;
    const int qq = nwg >> 3, rr = nwg & 7;
    const int xcd = bid & 7, jj = bid >> 3;
    const int swz = (xcd < rr ? xcd * (qq + 1) : rr * (qq + 1) + (xcd - rr) * qq) + jj;
    const int n0 = (swz % gx) * 64;
    const int m0 = (swz / gx) * 128;

    fv4 acc0[4] = {}, acc1[4] = {};

    for (int k0 = 0; k0 < K; k0 += 64) {
        #pragma unroll
        for (int i = 0; i < 2; ++i) {
            const int sb = (w * 2 + i) << 6;
            const int slot = sb + l;
            const int row = slot >> 3;
            const int gs = (slot & 7) ^ (row & 7);
            gll16(Wt + (size_t)(n0 + row) * K + k0 + gs * 8, Bs + sb * 8);
        }
        if constexpr (!AF32 && !AAFF) {
            const u16* Ab = (const u16*)Aptr;
            #pragma unroll
            for (int i = 0; i < 4; ++i) {
                const int sb = (w * 4 + i) << 6;
                const int slot = sb + l;
                const int row = slot >> 3;
                const int gs = (slot & 7) ^ (row & 7);
                int rg = m0 + row; if (rg > M - 1) rg = M - 1;
                gll16(Ab + (size_t)rg * K + k0 + gs * 8, As + sb * 8);
            }
        } else {
            const int row = t >> 1;
            int rg = m0 + row; if (rg > M - 1) rg = M - 1;
            const size_t gr = (size_t)rg;
            #pragma unroll
            for (int i = 0; i < 4; ++i) {
                const int g = ((t & 1) << 2) + i;
                const int kb = k0 + (g << 3);
                sv8 av;
                if constexpr (AF32) {
                    const float* Af = (const float*)Aptr;
                    fv4 u0 = *(const fv4*)(Af + gr * K + kb);
                    fv4 u1 = *(const fv4*)(Af + gr * K + kb + 4);
                    #pragma unroll
                    for (int j = 0; j < 4; ++j) { av[j] = (short)f2b(u0[j]); av[j + 4] = (short)f2b(u1[j]); }
                } else {
                    sv8 v = *(const sv8*)((const u16*)Aptr + gr * K + kb);
                    fv4 c0 = *(const fv4*)(sc + kb), c1 = *(const fv4*)(sc + kb + 4);
                    fv4 d0 = *(const fv4*)(sh + kb), d1 = *(const fv4*)(sh + kb + 4);
                    #pragma unroll
                    for (int j = 0; j < 4; ++j) {
                        av[j]     = (short)f2b(fmaxf(b2f((u16)v[j])     * c0[j] + d0[j], 0.f));
                        av[j + 4] = (short)f2b(fmaxf(b2f((u16)v[j + 4]) * c1[j] + d1[j], 0.f));
                    }
                }
                const int gs = g ^ (row & 7);
                *(sv8*)&As[(row * 8 + gs) * 8] = av;
            }
        }
        __syncthreads();

        #pragma unroll
        for (int kk = 0; kk < 2; ++kk) {
            const int ga = (kk << 2) + (l >> 4);
            const int Ar0 = (w << 4) + (l & 15);
            const int Ar1 = 64 + Ar0;
            sv8 a0 = *(const sv8*)&As[(Ar0 * 8 + (ga ^ (Ar0 & 7))) * 8];
            sv8 a1 = *(const sv8*)&As[(Ar1 * 8 + (ga ^ (Ar1 & 7))) * 8];
            #pragma unroll
            for (int ct = 0; ct < 4; ++ct) {
                const int Brow = (ct << 4) + (l & 15);
                sv8 b = *(const sv8*)&Bs[(Brow * 8 + (ga ^ (Brow & 7))) * 8];
                acc0[ct] = __builtin_amdgcn_mfma_f32_16x16x32_bf16(a0, b, acc0[ct], 0, 0, 0);
                acc1[ct] = __builtin_amdgcn_mfma_f32_16x16x32_bf16(a1, b, acc1[ct], 0, 0, 0);
            }
        }
        __syncthreads();
    }

    const int lr0 = (w << 4) + ((l >> 4) << 2);
    #pragma unroll
    for (int ct = 0; ct < 4; ++ct) {
        const int col = (ct << 4) + (l & 15);
        const float bv = bias[n0 + col];
        float s = 0.f, s2 = 0.f;
        #pragma unroll
        for (int h = 0; h < 2; ++h) {
            #pragma unroll
            for (int r = 0; r < 4; ++r) {
                const int lrow = (h << 6) + lr0 + r;
                const bool valid = (m0 + lrow) < M;
                float v = (h ? acc1[ct][r] : acc0[ct][r]) + bv;
                if constexpr (STATS) { if (valid) { s += v; s2 += v * v; } }
                if constexpr (EPI == 1) v = fmaxf(v, 0.f);
                if constexpr (EPI == 3) {
                    if (valid) ((float*)Cptr)[(size_t)(m0 + lrow) * F + n0 + col] = v;
                } else {
                    Cs[lrow * 68 + col] = f2b(v);
                }
            }
        }
        if constexpr (STATS) {
            s  += __shfl_xor(s, 16);  s  += __shfl_xor(s, 32);
            s2 += __shfl_xor(s2, 16); s2 += __shfl_xor(s2, 32);
            if (l < 16) { unsafeAtomicAdd(&sums[n0 + col], s); unsafeAtomicAdd(&sumsq[n0 + col], s2); }
        }
    }
    if constexpr (EPI != 3) {
        __syncthreads();
        const int row = t >> 1, c0 = (t & 1) << 5;
        if (m0 + row < M) {
            u16* Cb = (u16*)Cptr + (size_t)(m0 + row) * F + n0 + c0;
            #pragma unroll
            for (int j = 0; j < 4; ++j)
                *(sv8*)(Cb + j * 8) = *(const sv8*)&Cs[row * 68 + c0 + j * 8];
        }
    }
}

// ---------------------------------------------------------------------------
// Edge GEMM (R13/R16-proven): e[p][.] = bf16(ea[perm[p]]) @ Wt^T + bias.
// Bs-only LDS; A direct to registers; shfl-pack u32 stores.
// ---------------------------------------------------------------------------
template<int FN>
__global__ __launch_bounds__(256) void k_egemm3(
    const float* __restrict__ ea, const int* __restrict__ perm,
    const u16* __restrict__ Wt, const float* __restrict__ bias,
    u16* __restrict__ Cbuf)
{
    __shared__ u16 Bs[FN * 64];
    const int t = threadIdx.x, w = t >> 6, l = t & 63;
    const int m0 = blockIdx.x * 64;

    constexpr int BISS = FN / 32;        // B: FN rows x 8 granules of 16B
    #pragma unroll
    for (int i = 0; i < BISS; ++i) {
        int slot = ((w * BISS + i) << 6) + l;
        int row = slot >> 3, g = (slot & 7) ^ (row & 7);
        gll16(Wt + (size_t)row * 64 + g * 8, Bs + ((w * BISS + i) << 6) * 8);
    }

    const int g0 = l >> 4;
    const int gr = m0 + (w << 4) + (l & 15);
    const int prow = perm[gr];
    const float* ar = ea + (size_t)prow * 64 + (g0 << 3);
    fv4 u0 = *(const fv4*)ar;
    fv4 u1 = *(const fv4*)(ar + 4);
    fv4 u2 = *(const fv4*)(ar + 32);
    fv4 u3 = *(const fv4*)(ar + 36);
    sv8 a0, a1;
    #pragma unroll
    for (int j = 0; j < 4; ++j) {
        a0[j] = (short)f2b(u0[j]); a0[j + 4] = (short)f2b(u1[j]);
        a1[j] = (short)f2b(u2[j]); a1[j + 4] = (short)f2b(u3[j]);
    }
    __syncthreads();                     // Bs resident (vmcnt drained)

    fv4 acc[FN / 16];
    #pragma unroll
    for (int ct = 0; ct < FN / 16; ++ct) {
        int Brow = (ct << 4) + (l & 15);
        sv8 b0 = *(const sv8*)&Bs[(Brow * 8 + ((g0)     ^ (Brow & 7))) * 8];
        sv8 b1 = *(const sv8*)&Bs[(Brow * 8 + ((g0 + 4) ^ (Brow & 7))) * 8];
        fv4 z = {};
        z = __builtin_amdgcn_mfma_f32_16x16x32_bf16(a0, b0, z, 0, 0, 0);
        acc[ct] = __builtin_amdgcn_mfma_f32_16x16x32_bf16(a1, b1, z, 0, 0, 0);
    }

    const int r0 = (w << 4) + ((l >> 4) << 2);
    #pragma unroll
    for (int ct = 0; ct < FN / 16; ++ct) {
        const int col = (ct << 4) + (l & 15);
        const float bv = bias[col];
        #pragma unroll
        for (int r = 0; r < 4; ++r) {
            const int row = m0 + r0 + r;
            u32 my = (u32)f2b(acc[ct][r] + bv);
            u32 ot = (u32)__shfl_xor((int)my, 1);
            if (!(l & 1))
                *(u32*)(Cbuf + (size_t)row * FN + col) = (my & 0xFFFFu) | (ot << 16);
        }
    }
}

// --------------------------- CSR build (by dst) ----------------------------
__global__ void k_hist(const int* __restrict__ dst, int* __restrict__ counts, int E) {
    int i = blockIdx.x * 256 + threadIdx.x;
    if (i < E) atomicAdd(&counts[dst[i]], 1);
}

__global__ __launch_bounds__(256) void k_psum(const int* __restrict__ counts,
                                              int* __restrict__ bsum, int n) {
    int i = blockIdx.x * 256 + threadIdx.x;
    int v = (i < n) ? counts[i] : 0;
    #pragma unroll
    for (int o = 1; o < 64; o <<= 1) v += __shfl_xor(v, o);
    __shared__ int ws[4];
    if ((threadIdx.x & 63) == 0) ws[threadIdx.x >> 6] = v;
    __syncthreads();
    if (threadIdx.x == 0) bsum[blockIdx.x] = ws[0] + ws[1] + ws[2] + ws[3];
}

__global__ __launch_bounds__(256) void k_bscan(const int* __restrict__ bsum,
                                               int* __restrict__ boff, int nb) {
    __shared__ int sm[256];
    int t = threadIdx.x;
    int v = (t < nb) ? bsum[t] : 0;
    sm[t] = v; __syncthreads();
    #pragma unroll
    for (int o = 1; o < 256; o <<= 1) {
        int u = (t >= o) ? sm[t - o] : 0;
        __syncthreads();
        sm[t] += u;
        __syncthreads();
    }
    if (t < nb) boff[t] = sm[t] - v;
}

__global__ __launch_bounds__(256) void k_windp(const int* __restrict__ counts,
                                               const int* __restrict__ boff,
                                               int* __restrict__ indptr,
                                               int* __restrict__ cursors, int n) {
    __shared__ int sm[256];
    const int t = threadIdx.x, i = blockIdx.x * 256 + t;
    int v = (i < n) ? counts[i] : 0;
    sm[t] = v; __syncthreads();
    #pragma unroll
    for (int o = 1; o < 256; o <<= 1) {
        int u = (t >= o) ? sm[t - o] : 0;
        __syncthreads();
        sm[t] += u;
        __syncthreads();
    }
    int excl = sm[t] - v + boff[blockIdx.x];
    if (i < n) { indptr[i] = excl; cursors[i] = excl; }
    if (i == n - 1) indptr[n] = excl + v;
}

__global__ void k_scatter(const int* __restrict__ dst, const int* __restrict__ src,
                          int* __restrict__ cursors, int* __restrict__ perm,
                          int* __restrict__ srcp, int E) {
    int i = blockIdx.x * 256 + threadIdx.x;
    if (i < E) {
        int p = atomicAdd(&cursors[dst[i]], 1);
        perm[p] = i;
        srcp[p] = src[i];
    }
}

// ------------- softmax aggregation: msg = relu(e[p] + h[src[p]]) + eps -----
// 2-deep data pipeline + srcp prefetched two edges ahead (R14-16 proven).
template<int F, int VPT>
__global__ __launch_bounds__(256) void k_agg(
    const u16* __restrict__ e, const u16* __restrict__ hhd,
    const int* __restrict__ srcp, const int* __restrict__ indptr,
    u16* __restrict__ out, int N)
{
    const int nid = blockIdx.x * 4 + (threadIdx.x >> 6);
    if (nid >= N) return;
    const int c0 = (threadIdx.x & 63) * VPT;
    const int S = 2 * F;
    const int p0 = indptr[nid], p1 = indptr[nid + 1];
    float den[VPT] = {}, num[VPT] = {};

    auto LOADE = [&](int p, u16* ev) {
        if constexpr (VPT == 4) *(us4*)ev = *(const us4*)&e[(size_t)p * F + c0];
        else                    *(us2*)ev = *(const us2*)&e[(size_t)p * F + c0];
    };
    auto LOADH = [&](int s, u16* hv) {
        if constexpr (VPT == 4) *(us4*)hv = *(const us4*)&hhd[(size_t)s * S + c0];
        else                    *(us2*)hv = *(const us2*)&hhd[(size_t)s * S + c0];
    };
    auto ACCUM = [&](const u16* ev, const u16* hv) {
        #pragma unroll
        for (int j = 0; j < VPT; ++j) {
            float x = fmaxf(b2f(ev[j]) + b2f(hv[j]), 0.f) + 1e-7f;
            float ex = __expf(x);
            den[j] += ex;
            num[j] += ex * x;
        }
    };

    if (p0 < p1) {
        int sB = (p0 + 1 < p1) ? srcp[p0 + 1] : 0;
        u16 evA[VPT], hvA[VPT];
        LOADE(p0, evA); LOADH(srcp[p0], hvA);
        for (int p = p0 + 1; p < p1; ++p) {
            int sC = (p + 1 < p1) ? srcp[p + 1] : 0;
            u16 evB[VPT], hvB[VPT];
            LOADE(p, evB); LOADH(sB, hvB);
            ACCUM(evA, hvA);
            #pragma unroll
            for (int j = 0; j < VPT; ++j) { evA[j] = evB[j]; hvA[j] = hvB[j]; }
            sB = sC;
        }
        ACCUM(evA, hvA);
    }

    #pragma unroll
    for (int j = 0; j < VPT; ++j) {
        float o = num[j] / (den[j] + 1e-16f) + b2f(hhd[(size_t)nid * S + F + c0 + j]);
        out[(size_t)nid * F + c0 + j] = f2b(o);
    }
}

// ------------------- all weight converts in one kernel ---------------------
struct WtDesc { const float* W; u16* D; int K; int F; int end; };
struct WtPack { WtDesc d[10]; };

__global__ void k_wtall(WtPack p, int total) {
    int i = blockIdx.x * 256 + threadIdx.x;
    if (i >= total) return;
    int s = 0, base = 0;
    while (i >= p.d[s].end) { base = p.d[s].end; ++s; }
    int loc = i - base;
    int K = p.d[s].K, F = p.d[s].F;
    int f = loc / K, k = loc - f * K;
    p.d[s].D[loc] = f2b(p.d[s].W[(size_t)k * F + f]);
}

// ---- bias concats ---------------------------------------------------------
__global__ void k_bcat(const float* __restrict__ bsrc1, const float* __restrict__ bdst1,
                       const float* __restrict__ bsrc2, const float* __restrict__ bdst2,
                       float* __restrict__ bcat1, float* __restrict__ bcat2) {
    int t = threadIdx.x;
    bcat1[t] = bsrc1[t];
    bcat1[256 + t] = bdst1[t];
    if (t < 128) {
        bcat2[t] = bsrc2[t];
        bcat2[128 + t] = bdst2[t];
    }
}

// ----------------------------- BN finalize ---------------------------------
__global__ void k_bnfinal(const float* __restrict__ sums, const float* __restrict__ sumsq,
                          const float* __restrict__ g, const float* __restrict__ bt,
                          float* __restrict__ scale, float* __restrict__ shift,
                          int C, float invN)
{
    int c = blockIdx.x * 256 + threadIdx.x;
    if (c < C) {
        float mu  = sums[c] * invN;
        float var = sumsq[c] * invN - mu * mu;
        float s   = g[c] * rsqrtf(var + 1e-5f);
        scale[c] = s;
        shift[c] = bt[c] - mu * s;
    }
}

// ---------------------------------------------------------------------------
extern "C" void kernel_launch(void* const* d_in, const int* in_sizes, int n_in,
                              void* d_out, int out_size, void* d_ws, size_t ws_size,
                              hipStream_t stream)
{
    const int IN = 128, HID = 256, OUT = 128, ED = 64;
    const int N = in_sizes[0] / IN;
    const int E = in_sizes[1] / 2;

    const float* x   = (const float*)d_in[0];
    const int*   src = (const int*)d_in[1];
    const int*   dst = src + E;
    const float* ea  = (const float*)d_in[2];
    auto F32 = [&](int i) { return (const float*)d_in[i]; };
    const float *Wsrc1 = F32(3),  *bsrc1 = F32(4),  *Wdst1 = F32(5),  *bdst1 = F32(6),
                *We1   = F32(7),  *be1   = F32(8),  *W11   = F32(9),  *b11   = F32(10),
                *g1    = F32(11), *bt1   = F32(12), *W21   = F32(13), *b21   = F32(14);
    const float *Wsrc2 = F32(15), *bsrc2 = F32(16), *Wdst2 = F32(17), *bdst2 = F32(18),
                *We2   = F32(19), *be2   = F32(20), *W12   = F32(21), *b12   = F32(22),
                *g2    = F32(23), *bt2   = F32(24), *W22   = F32(25), *b22   = F32(26);

    char* wp = (char*)d_ws;
    auto carve = [&](size_t bytes) -> void* {
        void* r = (void*)wp; wp += (bytes + 255) & ~(size_t)255; return r;
    };
    u16* wcat1  = (u16*)carve((size_t)HID * IN * 2);
    u16* wdst1t = (u16*)carve((size_t)HID * IN * 2);
    u16* we1t   = (u16*)carve((size_t)HID * ED * 2);
    u16* w11t   = (u16*)carve((size_t)(2 * HID) * HID * 2);
    u16* w21t   = (u16*)carve((size_t)HID * (2 * HID) * 2);
    u16* wcat2  = (u16*)carve((size_t)OUT * HID * 2);
    u16* wdst2t = (u16*)carve((size_t)OUT * HID * 2);
    u16* we2t   = (u16*)carve((size_t)OUT * ED * 2);
    u16* w12t   = (u16*)carve((size_t)(2 * OUT) * OUT * 2);
    u16* w22t   = (u16*)carve((size_t)OUT * (2 * OUT) * 2);
    int* counts  = (int*)carve((size_t)N * 4);
    int* indptr  = (int*)carve((size_t)(N + 1) * 4);
    int* cursors = (int*)carve((size_t)N * 4);
    int* perm    = (int*)carve((size_t)E * 4);
    int* srcp    = (int*)carve((size_t)E * 4);
    int* bsum    = (int*)carve((size_t)256 * 4);
    int* boff    = (int*)carve((size_t)256 * 4);
    u16* hhd  = (u16*)carve((size_t)N * 512 * 2);
    u16* x2   = (u16*)carve((size_t)N * HID * 2);
    u16* ebuf = (u16*)carve((size_t)E * HID * 2);   // e rows; h1 aliases this
    float* stats1 = (float*)carve((size_t)1024 * 4);
    float* stats2 = (float*)carve((size_t)512 * 4);
    float* ss1    = (float*)carve((size_t)1024 * 4);
    float* ss2    = (float*)carve((size_t)512 * 4);
    float* bcat1  = (float*)carve((size_t)512 * 4);
    float* bcat2  = (float*)carve((size_t)256 * 4);
    u16* h1 = ebuf;   // lifetimes strictly interleave: e-L1, h1-L1, e-L2, h1-L2

    hipMemsetAsync(counts, 0, (size_t)N * 4, stream);
    hipMemsetAsync(stats1, 0, (size_t)(1024 + 512) * 4, stream);
    k_hist<<<dim3((E + 255) / 256), dim3(256), 0, stream>>>(dst, counts, E);
    const int nb = (N + 255) / 256;
    k_psum<<<dim3(nb), dim3(256), 0, stream>>>(counts, bsum, N);
    k_bscan<<<dim3(1), dim3(256), 0, stream>>>(bsum, boff, nb);
    k_windp<<<dim3(nb), dim3(256), 0, stream>>>(counts, boff, indptr, cursors, N);
    k_scatter<<<dim3((E + 255) / 256), dim3(256), 0, stream>>>(dst, src, cursors, perm, srcp, E);

    WtPack wpk; int acc_end = 0;
    auto addw = [&](int idx, const float* W, u16* D, int K, int F) {
        acc_end += K * F;
        wpk.d[idx] = WtDesc{W, D, K, F, acc_end};
    };
    addw(0, Wsrc1, wcat1,  IN, HID);   addw(1, Wdst1, wdst1t, IN, HID);
    addw(2, We1,   we1t,   ED, HID);   addw(3, W11,   w11t,   HID, 2 * HID);
    addw(4, W21,   w21t,   2 * HID, HID);
    addw(5, Wsrc2, wcat2,  HID, OUT);  addw(6, Wdst2, wdst2t, HID, OUT);
    addw(7, We2,   we2t,   ED, OUT);   addw(8, W12,   w12t,   OUT, 2 * OUT);
    addw(9, W22,   w22t,   2 * OUT, OUT);
    k_wtall<<<dim3((acc_end + 255) / 256), dim3(256), 0, stream>>>(wpk, acc_end);
    k_bcat<<<dim3(1), dim3(256), 0, stream>>>(bsrc1, bdst1, bsrc2, bdst2, bcat1, bcat2);

    const int gm = (N + 127) / 128;

    // ---------------- Layer 1 ----------------
    k_gemm<true, false, 0, false><<<dim3(8, gm), dim3(256), 0, stream>>>(
        x, wcat1, bcat1, hhd, N, IN, 512, nullptr, nullptr, nullptr, nullptr);
    k_egemm3<256><<<dim3(E / 64), dim3(256), 0, stream>>>(ea, perm, we1t, be1, ebuf);
    k_agg<256, 4><<<dim3((N + 3) / 4), dim3(256), 0, stream>>>(ebuf, hhd, srcp, indptr, x2, N);
    k_gemm<false, false, 0, true><<<dim3(8, gm), dim3(256), 0, stream>>>(
        x2, w11t, b11, h1, N, HID, 512, nullptr, nullptr, stats1, stats1 + 512);
    k_bnfinal<<<dim3(2), dim3(256), 0, stream>>>(
        stats1, stats1 + 512, g1, bt1, ss1, ss1 + 512, 512, 1.f / N);
    k_gemm<false, true, 1, false><<<dim3(4, gm), dim3(256), 0, stream>>>(
        h1, w21t, b21, x2, N, 512, HID, ss1, ss1 + 512, nullptr, nullptr);

    // ---------------- Layer 2 ----------------
    k_gemm<false, false, 0, false><<<dim3(4, gm), dim3(256), 0, stream>>>(
        x2, wcat2, bcat2, hhd, N, HID, 256, nullptr, nullptr, nullptr, nullptr);
    k_egemm3<128><<<dim3(E / 64), dim3(256), 0, stream>>>(ea, perm, we2t, be2, ebuf);
    k_agg<128, 2><<<dim3((N + 3) / 4), dim3(256), 0, stream>>>(ebuf, hhd, srcp, indptr, x2, N);
    k_gemm<false, false, 0, true><<<dim3(4, gm), dim3(256), 0, stream>>>(
        x2, w12t, b12, h1, N, OUT, 256, nullptr, nullptr, stats2, stats2 + 256);
    k_bnfinal<<<dim3(1), dim3(256), 0, stream>>>(
        stats2, stats2 + 256, g2, bt2, ss2, ss2 + 256, 256, 1.f / N);
    k_gemm<false, true, 3, false><<<dim3(2, gm), dim3(256), 0, stream>>>(
        h1, w22t, b22, d_out, N, HID, OUT, ss2, ss2 + 256, nullptr, nullptr);
}